// Round 2
// baseline (620.360 us; speedup 1.0000x reference)
//
#include <hip/hip_runtime.h>
#include <stdint.h>
#include <math.h>

#define NTOK   2048
#define DDIM   1024
#define ENUM   8
#define IDIM   2048
#define TWOI   4096
#define TOPKN  4
#define CAPROWS 9216   // max padded routed rows: 8*2048 actual <= 8192, +8*127 pad -> 9208, round 9216

typedef unsigned short ushort_t;
typedef __attribute__((ext_vector_type(8))) short short8;
typedef __attribute__((ext_vector_type(4))) float f4;

__device__ inline ushort_t f2bf(float f) {
    union { float f; uint32_t u; } v; v.f = f;
    uint32_t u = v.u;
    u += 0x7FFFu + ((u >> 16) & 1u);   // round-to-nearest-even
    return (ushort_t)(u >> 16);
}
__device__ inline float bf2f(uint32_t b) {
    union { uint32_t u; float f; } v; v.u = b << 16;
    return v.f;
}

// async global->LDS 16B per lane (gfx950). LDS dest must be wave-uniform base + lane*16.
__device__ inline void gload16(const ushort_t* g, ushort_t* l) {
    __builtin_amdgcn_global_load_lds(
        (const __attribute__((address_space(1))) uint32_t*)(uintptr_t)g,
        (__attribute__((address_space(3))) uint32_t*)(uint32_t)(uintptr_t)l,
        16, 0, 0);
}

// ---------------- weight fp32 -> bf16 conversion ----------------
__global__ void cvt_kernel(const float* __restrict__ src, ushort_t* __restrict__ dst, int n4) {
    int i = blockIdx.x * 256 + threadIdx.x;
    if (i >= n4) return;
    float4 v = ((const float4*)src)[i];
    ushort4 o; o.x = f2bf(v.x); o.y = f2bf(v.y); o.z = f2bf(v.z); o.w = f2bf(v.w);
    ((ushort4*)dst)[i] = o;
}

__global__ void zero_meta_kernel(int* meta) {
    if (blockIdx.x == 0 && threadIdx.x < 64) meta[threadIdx.x] = 0;
}

// ---------------- router: fp64 logits (robust top-4 vs fp32 reference noise), fp32 softmax ----
__global__ void router_kernel(const float* __restrict__ x, const float* __restrict__ rw,
                              const float* __restrict__ rb, int* __restrict__ topk_idx,
                              float* __restrict__ topk_w, int* __restrict__ counts) {
    int n = (blockIdx.x * 256 + threadIdx.x) >> 6;   // one wave per token
    int lane = threadIdx.x & 63;
    const float* xr = x + (size_t)n * DDIM;
    double p[ENUM];
#pragma unroll
    for (int e = 0; e < ENUM; ++e) p[e] = 0.0;
    for (int d0 = 0; d0 < DDIM; d0 += 64) {
        double xv = (double)xr[d0 + lane];
#pragma unroll
        for (int e = 0; e < ENUM; ++e) p[e] += xv * (double)rw[e * DDIM + d0 + lane];
    }
#pragma unroll
    for (int e = 0; e < ENUM; ++e) {
        double v = p[e];
#pragma unroll
        for (int off = 32; off > 0; off >>= 1) v += __shfl_xor(v, off, 64);
        p[e] = v + (double)rb[e];
    }
    if (lane == 0) {
        int id[TOPKN]; double lv[TOPKN]; unsigned used = 0;
#pragma unroll
        for (int k = 0; k < TOPKN; ++k) {
            double best = -INFINITY; int bi = 0;
            for (int e = 0; e < ENUM; ++e)
                if (!((used >> e) & 1u) && p[e] > best) { best = p[e]; bi = e; }
            used |= 1u << bi; id[k] = bi; lv[k] = best;
        }
        // softmax in fp32 on fp32-cast logits (matches reference dtype flow)
        float lf[TOPKN]; float s = 0.f;
#pragma unroll
        for (int k = 0; k < TOPKN; ++k) lf[k] = (float)lv[k];
        float w[TOPKN];
#pragma unroll
        for (int k = 0; k < TOPKN; ++k) { w[k] = expf(lf[k] - lf[0]); s += w[k]; }
        float inv = 1.f / s;
#pragma unroll
        for (int k = 0; k < TOPKN; ++k) {
            topk_idx[n * TOPKN + k] = id[k];
            topk_w[n * TOPKN + k] = w[k] * inv;
            atomicAdd(&counts[id[k]], 1);
        }
    }
}

// ---------------- prefix over experts (pad to 128) ----------------
__global__ void scan_kernel(const int* __restrict__ counts, int* __restrict__ base,
                            int* __restrict__ padcnt, int* __restrict__ totalp) {
    if (blockIdx.x == 0 && threadIdx.x == 0) {
        int run = 0;
        for (int e = 0; e < ENUM; ++e) {
            base[e] = run;
            int pc = (counts[e] + 127) & ~127;
            padcnt[e] = pc;
            run += pc;
        }
        *totalp = run;
    }
}

// ---------------- assign routed rows ----------------
__global__ void assign_kernel(const int* __restrict__ topk_idx, const float* __restrict__ topk_w,
                              const int* __restrict__ base, int* __restrict__ fill,
                              int* __restrict__ row_token, float* __restrict__ row_weight,
                              int* __restrict__ row_of_pair) {
    int n = blockIdx.x * 256 + threadIdx.x;
    if (n >= NTOK) return;
    for (int k = 0; k < TOPKN; ++k) {
        int e = topk_idx[n * TOPKN + k];
        int pos = atomicAdd(&fill[e], 1);
        int row = base[e] + pos;
        row_token[row] = n;
        row_weight[row] = topk_w[n * TOPKN + k];
        row_of_pair[n * TOPKN + k] = row;
    }
}

// ---------------- gather tokens -> bf16 A matrix (zero pad rows) ----------------
__global__ void gather_kernel(const float* __restrict__ x, const int* __restrict__ row_token,
                              const int* __restrict__ base, const int* __restrict__ counts,
                              const int* __restrict__ padcnt, const int* __restrict__ totalp,
                              ushort_t* __restrict__ A) {
    int r = blockIdx.x;
    if (r >= *totalp) return;
    int e = 0;
#pragma unroll
    for (int i = 0; i < ENUM; ++i) if (r >= base[i] + padcnt[i]) e = i + 1;
    bool valid = (r - base[e]) < counts[e];
    int t = threadIdx.x;
    float4 v = make_float4(0.f, 0.f, 0.f, 0.f);
    if (valid) {
        int n = row_token[r];
        v = ((const float4*)(x + (size_t)n * DDIM))[t];
    }
    ushort4 o; o.x = f2bf(v.x); o.y = f2bf(v.y); o.z = f2bf(v.z); o.w = f2bf(v.w);
    ((ushort4*)(A + (size_t)r * DDIM))[t] = o;
}

// ---------------- shared MFMA tile loop: C[128x128] += A[128xK] * B[128xK]^T ----------------
// block = 256 threads = 4 waves in 2x2; wave computes 64x64 via 4x4 of 16x16x32 MFMA.
__device__ inline void gemm_tiles(const ushort_t* __restrict__ Ag, int lda,
                                  const ushort_t* __restrict__ Bg, int ldb,
                                  int kdim, ushort_t* ldsA, ushort_t* ldsB,
                                  f4 acc[4][4]) {
    const int t = threadIdx.x;
    const int lane = t & 63;
    const int wid = t >> 6;
    const int wm = wid >> 1, wn = wid & 1;
    const int r15 = lane & 15, quad = lane >> 4;
    const int sr = t >> 2;            // staging row 0..63
    const int sc = (t & 3) << 3;      // staging col {0,8,16,24}

    const ushort_t* aA  = Ag + (size_t)sr * lda + sc;
    const ushort_t* aA2 = Ag + (size_t)(sr + 64) * lda + sc;
    const ushort_t* aB  = Bg + (size_t)sr * ldb + sc;
    const ushort_t* aB2 = Bg + (size_t)(sr + 64) * ldb + sc;
    ushort_t* lA  = ldsA + sr * 32 + sc;
    ushort_t* lA2 = ldsA + (sr + 64) * 32 + sc;
    ushort_t* lB  = ldsB + sr * 32 + sc;
    ushort_t* lB2 = ldsB + (sr + 64) * 32 + sc;

    for (int k0 = 0; k0 < kdim; k0 += 32) {
        __syncthreads();                 // protect LDS from previous iter's readers
        gload16(aA + k0, lA);
        gload16(aA2 + k0, lA2);
        gload16(aB + k0, lB);
        gload16(aB2 + k0, lB2);
        __syncthreads();                 // drains vmcnt before barrier (gfx950 semantics)
        short8 af[4], bfv[4];
#pragma unroll
        for (int i = 0; i < 4; ++i) {
            af[i]  = *(const short8*)(ldsA + (wm * 64 + i * 16 + r15) * 32 + quad * 8);
            bfv[i] = *(const short8*)(ldsB + (wn * 64 + i * 16 + r15) * 32 + quad * 8);
        }
#pragma unroll
        for (int mi = 0; mi < 4; ++mi)
#pragma unroll
            for (int ni = 0; ni < 4; ++ni)
                acc[mi][ni] = __builtin_amdgcn_mfma_f32_16x16x32_bf16(af[mi], bfv[ni], acc[mi][ni], 0, 0, 0);
    }
}

// ---------------- GEMM1: gate_up = A_routed @ Wg^T + bias (bf16 out) ----------------
__global__ void gemm1_kernel(const ushort_t* __restrict__ A, const ushort_t* __restrict__ Wg,
                             const float* __restrict__ gub, ushort_t* __restrict__ gate_up,
                             const int* __restrict__ base, const int* __restrict__ padcnt) {
    const int e = blockIdx.z;
    const int mt = blockIdx.y;
    if (mt * 128 >= padcnt[e]) return;
    const int nt = blockIdx.x;
    const int row0 = base[e] + mt * 128;
    __shared__ ushort_t ldsA[128 * 32];
    __shared__ ushort_t ldsB[128 * 32];
    f4 acc[4][4];
    const f4 zero = {0.f, 0.f, 0.f, 0.f};
#pragma unroll
    for (int i = 0; i < 4; ++i)
#pragma unroll
        for (int j = 0; j < 4; ++j) acc[i][j] = zero;

    gemm_tiles(A + (size_t)row0 * DDIM, DDIM,
               Wg + ((size_t)e * TWOI + (size_t)nt * 128) * DDIM, DDIM,
               DDIM, ldsA, ldsB, acc);

    const int t = threadIdx.x, lane = t & 63, wid = t >> 6;
    const int wm = wid >> 1, wn = wid & 1, r15 = lane & 15, quad = lane >> 4;
    const int colbase = nt * 128 + wn * 64;
    const int rowbase = row0 + wm * 64;
#pragma unroll
    for (int ni = 0; ni < 4; ++ni) {
        const int col = colbase + ni * 16 + r15;
        const float b = gub[e * TWOI + col];
#pragma unroll
        for (int mi = 0; mi < 4; ++mi) {
#pragma unroll
            for (int r = 0; r < 4; ++r) {
                const int row = rowbase + mi * 16 + quad * 4 + r;
                gate_up[(size_t)row * TWOI + col] = f2bf(acc[mi][ni][r] + b);
            }
        }
    }
}

// ---------------- clamped SwiGLU ----------------
__global__ void act_kernel(const ushort_t* __restrict__ gate_up, ushort_t* __restrict__ act,
                           const int* __restrict__ totalp) {
    int r = blockIdx.x;
    if (r >= *totalp) return;
    int t = threadIdx.x;
    const uint4* g4 = (const uint4*)(gate_up + (size_t)r * TWOI);
    uint4 g = g4[t];          // gate: elems t*8 .. t*8+7
    uint4 u = g4[t + 256];    // up:   elems 2048 + t*8 ..
    uint32_t gi[4] = {g.x, g.y, g.z, g.w};
    uint32_t ui[4] = {u.x, u.y, u.z, u.w};
    uint32_t oi[4];
#pragma unroll
    for (int i = 0; i < 4; ++i) {
        float g0 = bf2f(gi[i] & 0xffffu), g1 = bf2f(gi[i] >> 16);
        float u0 = bf2f(ui[i] & 0xffffu), u1 = bf2f(ui[i] >> 16);
        g0 = fminf(g0, 7.0f); g1 = fminf(g1, 7.0f);
        u0 = fminf(fmaxf(u0, -7.0f), 7.0f);
        u1 = fminf(fmaxf(u1, -7.0f), 7.0f);
        float a0 = (u0 + 1.0f) * g0 / (1.0f + __expf(-1.702f * g0));
        float a1 = (u1 + 1.0f) * g1 / (1.0f + __expf(-1.702f * g1));
        oi[i] = (uint32_t)f2bf(a0) | ((uint32_t)f2bf(a1) << 16);
    }
    uint4 o; o.x = oi[0]; o.y = oi[1]; o.z = oi[2]; o.w = oi[3];
    ((uint4*)(act + (size_t)r * IDIM))[t] = o;
}

// ---------------- GEMM2: contrib = (act @ Wd^T + bias) * route_weight (fp32 out) ----------------
__global__ void gemm2_kernel(const ushort_t* __restrict__ A, const ushort_t* __restrict__ Wd,
                             const float* __restrict__ dwb, const float* __restrict__ row_weight,
                             float* __restrict__ contrib,
                             const int* __restrict__ base, const int* __restrict__ padcnt) {
    const int e = blockIdx.z;
    const int mt = blockIdx.y;
    if (mt * 128 >= padcnt[e]) return;
    const int nt = blockIdx.x;
    const int row0 = base[e] + mt * 128;
    __shared__ ushort_t ldsA[128 * 32];
    __shared__ ushort_t ldsB[128 * 32];
    f4 acc[4][4];
    const f4 zero = {0.f, 0.f, 0.f, 0.f};
#pragma unroll
    for (int i = 0; i < 4; ++i)
#pragma unroll
        for (int j = 0; j < 4; ++j) acc[i][j] = zero;

    gemm_tiles(A + (size_t)row0 * IDIM, IDIM,
               Wd + ((size_t)e * DDIM + (size_t)nt * 128) * IDIM, IDIM,
               IDIM, ldsA, ldsB, acc);

    const int t = threadIdx.x, lane = t & 63, wid = t >> 6;
    const int wm = wid >> 1, wn = wid & 1, r15 = lane & 15, quad = lane >> 4;
    const int colbase = nt * 128 + wn * 64;
    const int rowbase = row0 + wm * 64;
#pragma unroll
    for (int mi = 0; mi < 4; ++mi) {
#pragma unroll
        for (int r = 0; r < 4; ++r) {
            const int row = rowbase + mi * 16 + quad * 4 + r;
            const float w = row_weight[row];
#pragma unroll
            for (int ni = 0; ni < 4; ++ni) {
                const int col = colbase + ni * 16 + r15;
                contrib[(size_t)row * DDIM + col] = (acc[mi][ni][r] + dwb[e * DDIM + col]) * w;
            }
        }
    }
}

// ---------------- combine 4 contributions per token ----------------
__global__ void combine_kernel(const float* __restrict__ contrib, const int* __restrict__ row_of_pair,
                               float* __restrict__ out) {
    int n = blockIdx.x;
    int t = threadIdx.x;
    int r0 = row_of_pair[n * 4 + 0], r1 = row_of_pair[n * 4 + 1];
    int r2 = row_of_pair[n * 4 + 2], r3 = row_of_pair[n * 4 + 3];
    float4 a = ((const float4*)(contrib + (size_t)r0 * DDIM))[t];
    float4 b = ((const float4*)(contrib + (size_t)r1 * DDIM))[t];
    float4 c = ((const float4*)(contrib + (size_t)r2 * DDIM))[t];
    float4 d = ((const float4*)(contrib + (size_t)r3 * DDIM))[t];
    float4 s;
    s.x = a.x + b.x + c.x + d.x;
    s.y = a.y + b.y + c.y + d.y;
    s.z = a.z + b.z + c.z + d.z;
    s.w = a.w + b.w + c.w + d.w;
    ((float4*)(out + (size_t)n * DDIM))[t] = s;
}

extern "C" void kernel_launch(void* const* d_in, const int* in_sizes, int n_in,
                              void* d_out, int out_size, void* d_ws, size_t ws_size,
                              hipStream_t stream) {
    const float* x   = (const float*)d_in[0];
    const float* rw  = (const float*)d_in[1];
    const float* rb  = (const float*)d_in[2];
    const float* gup = (const float*)d_in[3];
    const float* gub = (const float*)d_in[4];
    const float* dwn = (const float*)d_in[5];
    const float* dwb = (const float*)d_in[6];
    float* out = (float*)d_out;

    char* ws = (char*)d_ws;
    size_t off = 0;
    auto alloc = [&](size_t bytes) -> void* {
        void* p = ws + off;
        off += (bytes + 255) & ~(size_t)255;
        return p;
    };
    ushort_t* Wg   = (ushort_t*)alloc((size_t)ENUM * TWOI * DDIM * 2);  // 67.1 MB
    ushort_t* Wd   = (ushort_t*)alloc((size_t)ENUM * DDIM * IDIM * 2);  // 33.6 MB
    ushort_t* Ar   = (ushort_t*)alloc((size_t)CAPROWS * DDIM * 2);      // 18.9 MB
    ushort_t* GU   = (ushort_t*)alloc((size_t)CAPROWS * TWOI * 2);      // 75.5 MB
    ushort_t* ACT  = (ushort_t*)alloc((size_t)CAPROWS * IDIM * 2);      // 37.7 MB
    int*   topk_idx    = (int*)alloc(NTOK * 4 * 4);
    float* topk_w      = (float*)alloc(NTOK * 4 * 4);
    int*   row_of_pair = (int*)alloc(NTOK * 4 * 4);
    int*   row_token   = (int*)alloc(CAPROWS * 4);
    float* row_weight  = (float*)alloc(CAPROWS * 4);
    int*   meta        = (int*)alloc(256);
    // contrib aliases Wg: Wg's last reader is gemm1; contrib is written by gemm2 (later on stream)
    // and rewritten by cvt at the start of the NEXT launch (after combine consumed it). 37.7 <= 67.1 MB.
    float* CONTRIB = (float*)Wg;
    int* counts = meta;      int* fill = meta + 8;
    int* base   = meta + 16; int* padcnt = meta + 24;
    int* totalp = meta + 32;

    zero_meta_kernel<<<1, 64, 0, stream>>>(meta);
    cvt_kernel<<<(ENUM * TWOI * DDIM / 4 + 255) / 256, 256, 0, stream>>>(gup, Wg, ENUM * TWOI * DDIM / 4);
    cvt_kernel<<<(ENUM * DDIM * IDIM / 4 + 255) / 256, 256, 0, stream>>>(dwn, Wd, ENUM * DDIM * IDIM / 4);
    router_kernel<<<NTOK / 4, 256, 0, stream>>>(x, rw, rb, topk_idx, topk_w, counts);
    scan_kernel<<<1, 64, 0, stream>>>(counts, base, padcnt, totalp);
    assign_kernel<<<NTOK / 256, 256, 0, stream>>>(topk_idx, topk_w, base, fill, row_token, row_weight, row_of_pair);
    gather_kernel<<<CAPROWS, 256, 0, stream>>>(x, row_token, base, counts, padcnt, totalp, Ar);
    gemm1_kernel<<<dim3(TWOI / 128, 16, ENUM), 256, 0, stream>>>(Ar, Wg, gub, GU, base, padcnt);
    act_kernel<<<CAPROWS, 256, 0, stream>>>(GU, ACT, totalp);
    gemm2_kernel<<<dim3(DDIM / 128, 16, ENUM), 256, 0, stream>>>(ACT, Wd, dwb, row_weight, CONTRIB, base, padcnt);
    combine_kernel<<<NTOK, 256, 0, stream>>>(CONTRIB, row_of_pair, out);
}

// Round 3
// 589.117 us; speedup vs baseline: 1.0530x; 1.0530x over previous
//
#include <hip/hip_runtime.h>
#include <stdint.h>
#include <math.h>

#define NTOK   2048
#define DDIM   1024
#define ENUM   8
#define IDIM   2048
#define TWOI   4096
#define TOPKN  4
#define CAPROWS 9216   // max padded routed rows: 8192 + 8*127 = 9208 -> 9216

typedef unsigned short ushort_t;
typedef __attribute__((ext_vector_type(8))) short short8;
typedef __attribute__((ext_vector_type(4))) float f4;

__device__ inline ushort_t f2bf(float f) {
    union { float f; uint32_t u; } v; v.f = f;
    uint32_t u = v.u;
    u += 0x7FFFu + ((u >> 16) & 1u);   // RNE
    return (ushort_t)(u >> 16);
}
__device__ inline float bf2f(uint32_t b) {
    union { uint32_t u; float f; } v; v.u = b << 16;
    return v.f;
}

// async global->LDS 16B/lane (gfx950). LDS dest = wave-uniform base + lane*16.
__device__ inline void gload16(const ushort_t* g, ushort_t* l) {
    __builtin_amdgcn_global_load_lds(
        (const __attribute__((address_space(1))) uint32_t*)(uintptr_t)g,
        (__attribute__((address_space(3))) uint32_t*)(uint32_t)(uintptr_t)l,
        16, 0, 0);
}

__global__ void zero_meta_kernel(int* meta) {
    if (blockIdx.x == 0 && threadIdx.x < 64) meta[threadIdx.x] = 0;
}

// ---------------- fp32 -> bf16 for both weight tensors (Wd contiguous after Wg) ----
__global__ void cvt_all_kernel(const float* __restrict__ gup, const float* __restrict__ dwn,
                               ushort_t* __restrict__ dst) {
    const int n1 = ENUM * TWOI * DDIM / 4;   // float4 units
    const int n2 = ENUM * DDIM * IDIM / 4;
    int i = blockIdx.x * 256 + threadIdx.x;
    float4 v;
    if (i < n1) v = ((const float4*)gup)[i];
    else if (i < n1 + n2) v = ((const float4*)dwn)[i - n1];
    else return;
    ushort4 o; o.x = f2bf(v.x); o.y = f2bf(v.y); o.z = f2bf(v.z); o.w = f2bf(v.w);
    ((ushort4*)dst)[i] = o;
}

// ---------------- router: fp64 logits (top-4 robust vs fp32 ref noise), fp32 softmax ----
__global__ void router_kernel(const float* __restrict__ x, const float* __restrict__ rw,
                              const float* __restrict__ rb, int* __restrict__ topk_idx,
                              float* __restrict__ topk_w, int* __restrict__ counts) {
    int n = (blockIdx.x * 256 + threadIdx.x) >> 6;   // one wave per token
    int lane = threadIdx.x & 63;
    const float* xr = x + (size_t)n * DDIM;
    double p[ENUM];
#pragma unroll
    for (int e = 0; e < ENUM; ++e) p[e] = 0.0;
    for (int d0 = 0; d0 < DDIM; d0 += 64) {
        double xv = (double)xr[d0 + lane];
#pragma unroll
        for (int e = 0; e < ENUM; ++e) p[e] += xv * (double)rw[e * DDIM + d0 + lane];
    }
#pragma unroll
    for (int e = 0; e < ENUM; ++e) {
        double v = p[e];
#pragma unroll
        for (int off = 32; off > 0; off >>= 1) v += __shfl_xor(v, off, 64);
        p[e] = v + (double)rb[e];
    }
    if (lane == 0) {
        int id[TOPKN]; double lv[TOPKN]; unsigned used = 0;
#pragma unroll
        for (int k = 0; k < TOPKN; ++k) {
            double best = -INFINITY; int bi = 0;
            for (int e = 0; e < ENUM; ++e)
                if (!((used >> e) & 1u) && p[e] > best) { best = p[e]; bi = e; }
            used |= 1u << bi; id[k] = bi; lv[k] = best;
        }
        float lf[TOPKN]; float s = 0.f; float w[TOPKN];
#pragma unroll
        for (int k = 0; k < TOPKN; ++k) lf[k] = (float)lv[k];
#pragma unroll
        for (int k = 0; k < TOPKN; ++k) { w[k] = expf(lf[k] - lf[0]); s += w[k]; }
        float inv = 1.f / s;
#pragma unroll
        for (int k = 0; k < TOPKN; ++k) {
            topk_idx[n * TOPKN + k] = id[k];
            topk_w[n * TOPKN + k] = w[k] * inv;
            atomicAdd(&counts[id[k]], 1);
        }
    }
}

// ---------------- assign routed rows (scan inlined: every thread computes prefix) ----
__global__ void assign_kernel(const int* __restrict__ topk_idx, const float* __restrict__ topk_w,
                              const int* __restrict__ counts, int* __restrict__ fill,
                              int* __restrict__ row_token, float* __restrict__ row_weight,
                              int* __restrict__ row_of_pair,
                              int* __restrict__ base, int* __restrict__ padcnt,
                              int* __restrict__ totalp) {
    int baseL[ENUM]; int run = 0;
#pragma unroll
    for (int e = 0; e < ENUM; ++e) {
        baseL[e] = run;
        run += (counts[e] + 127) & ~127;
    }
    int n = blockIdx.x * 256 + threadIdx.x;
    if (n == 0) {
#pragma unroll
        for (int e = 0; e < ENUM; ++e) {
            base[e] = baseL[e];
            padcnt[e] = (counts[e] + 127) & ~127;
        }
        *totalp = run;
    }
    if (n >= NTOK) return;
    for (int k = 0; k < TOPKN; ++k) {
        int e = topk_idx[n * TOPKN + k];
        int pos = atomicAdd(&fill[e], 1);
        int row = baseL[e] + pos;
        row_token[row] = n;
        row_weight[row] = topk_w[n * TOPKN + k];
        row_of_pair[n * TOPKN + k] = row;
    }
}

// ---------------- gather tokens -> bf16 A matrix (zero pad rows) ----------------
__global__ void gather_kernel(const float* __restrict__ x, const int* __restrict__ row_token,
                              const int* __restrict__ base, const int* __restrict__ counts,
                              const int* __restrict__ padcnt, const int* __restrict__ totalp,
                              ushort_t* __restrict__ A) {
    int r = blockIdx.x;
    if (r >= *totalp) return;
    int e = 0;
#pragma unroll
    for (int i = 0; i < ENUM; ++i) if (r >= base[i] + padcnt[i]) e = i + 1;
    bool valid = (r - base[e]) < counts[e];
    int t = threadIdx.x;
    float4 v = make_float4(0.f, 0.f, 0.f, 0.f);
    if (valid) {
        int n = row_token[r];
        v = ((const float4*)(x + (size_t)n * DDIM))[t];
    }
    ushort4 o; o.x = f2bf(v.x); o.y = f2bf(v.y); o.z = f2bf(v.z); o.w = f2bf(v.w);
    ((ushort4*)(A + (size_t)r * DDIM))[t] = o;
}

// ---------------- GEMM1 fused: act = swiglu(A@Wgate^T + bg, A@Wup^T + bu) -------------
// block 256 = 4 waves (2x2); per k-iter: stage A, Bgate, Bup tiles; 32 MFMA.
__global__ __launch_bounds__(256, 2)
void gemm1_kernel(const ushort_t* __restrict__ A, const ushort_t* __restrict__ Wg,
                  const float* __restrict__ gub, ushort_t* __restrict__ act,
                  const int* __restrict__ base, const int* __restrict__ padcnt) {
    const int e = blockIdx.z;
    const int mt = blockIdx.y;
    if (mt * 128 >= padcnt[e]) return;
    const int nt = blockIdx.x;               // 0..15 -> cols of I dim
    const int row0 = base[e] + mt * 128;
    __shared__ ushort_t ldsA[128 * 32];
    __shared__ ushort_t ldsG[128 * 32];
    __shared__ ushort_t ldsU[128 * 32];
    f4 accg[4][4], accu[4][4];
    const f4 zero = {0.f, 0.f, 0.f, 0.f};
#pragma unroll
    for (int i = 0; i < 4; ++i)
#pragma unroll
        for (int j = 0; j < 4; ++j) { accg[i][j] = zero; accu[i][j] = zero; }

    const int t = threadIdx.x;
    const int lane = t & 63;
    const int wid = t >> 6;
    const int wm = wid >> 1, wn = wid & 1;
    const int r15 = lane & 15, quad = lane >> 4;
    const int sr = t >> 2;
    const int sc = (t & 3) << 3;

    const ushort_t* Ag = A + (size_t)row0 * DDIM;
    const ushort_t* Bg = Wg + ((size_t)e * TWOI + (size_t)nt * 128) * DDIM;
    const ushort_t* Bu = Wg + ((size_t)e * TWOI + IDIM + (size_t)nt * 128) * DDIM;

    const ushort_t* aA  = Ag + (size_t)sr * DDIM + sc;
    const ushort_t* aA2 = Ag + (size_t)(sr + 64) * DDIM + sc;
    const ushort_t* aG  = Bg + (size_t)sr * DDIM + sc;
    const ushort_t* aG2 = Bg + (size_t)(sr + 64) * DDIM + sc;
    const ushort_t* aU  = Bu + (size_t)sr * DDIM + sc;
    const ushort_t* aU2 = Bu + (size_t)(sr + 64) * DDIM + sc;
    ushort_t* lA  = ldsA + sr * 32 + sc;  ushort_t* lA2 = ldsA + (sr + 64) * 32 + sc;
    ushort_t* lG  = ldsG + sr * 32 + sc;  ushort_t* lG2 = ldsG + (sr + 64) * 32 + sc;
    ushort_t* lU  = ldsU + sr * 32 + sc;  ushort_t* lU2 = ldsU + (sr + 64) * 32 + sc;

    for (int k0 = 0; k0 < DDIM; k0 += 32) {
        __syncthreads();
        gload16(aA + k0, lA);   gload16(aA2 + k0, lA2);
        gload16(aG + k0, lG);   gload16(aG2 + k0, lG2);
        gload16(aU + k0, lU);   gload16(aU2 + k0, lU2);
        __syncthreads();
        short8 af[4], gf[4], uf[4];
#pragma unroll
        for (int i = 0; i < 4; ++i) {
            af[i] = *(const short8*)(ldsA + (wm * 64 + i * 16 + r15) * 32 + quad * 8);
            gf[i] = *(const short8*)(ldsG + (wn * 64 + i * 16 + r15) * 32 + quad * 8);
            uf[i] = *(const short8*)(ldsU + (wn * 64 + i * 16 + r15) * 32 + quad * 8);
        }
#pragma unroll
        for (int mi = 0; mi < 4; ++mi)
#pragma unroll
            for (int ni = 0; ni < 4; ++ni) {
                accg[mi][ni] = __builtin_amdgcn_mfma_f32_16x16x32_bf16(af[mi], gf[ni], accg[mi][ni], 0, 0, 0);
                accu[mi][ni] = __builtin_amdgcn_mfma_f32_16x16x32_bf16(af[mi], uf[ni], accu[mi][ni], 0, 0, 0);
            }
    }

    const int colbase = nt * 128 + wn * 64;
    const int rowbase = row0 + wm * 64;
#pragma unroll
    for (int ni = 0; ni < 4; ++ni) {
        const int col = colbase + ni * 16 + r15;            // 0..2047 (I dim)
        const float bg = gub[e * TWOI + col];
        const float bu = gub[e * TWOI + IDIM + col];
#pragma unroll
        for (int mi = 0; mi < 4; ++mi) {
#pragma unroll
            for (int r = 0; r < 4; ++r) {
                const int row = rowbase + mi * 16 + quad * 4 + r;
                float g = fminf(accg[mi][ni][r] + bg, 7.0f);
                float u = fminf(fmaxf(accu[mi][ni][r] + bu, -7.0f), 7.0f);
                float a = (u + 1.0f) * g / (1.0f + __expf(-1.702f * g));
                act[(size_t)row * IDIM + col] = f2bf(a);
            }
        }
    }
}

// ---------------- GEMM2: contrib = (act @ Wd^T + bias) * route_weight (fp32 out) ------
__global__ void gemm2_kernel(const ushort_t* __restrict__ A, const ushort_t* __restrict__ Wd,
                             const float* __restrict__ dwb, const float* __restrict__ row_weight,
                             float* __restrict__ contrib,
                             const int* __restrict__ base, const int* __restrict__ padcnt) {
    const int e = blockIdx.z;
    const int mt = blockIdx.y;
    if (mt * 128 >= padcnt[e]) return;
    const int nt = blockIdx.x;
    const int row0 = base[e] + mt * 128;
    __shared__ ushort_t ldsA[128 * 32];
    __shared__ ushort_t ldsB[128 * 32];
    f4 acc[4][4];
    const f4 zero = {0.f, 0.f, 0.f, 0.f};
#pragma unroll
    for (int i = 0; i < 4; ++i)
#pragma unroll
        for (int j = 0; j < 4; ++j) acc[i][j] = zero;

    const int t = threadIdx.x;
    const int lane = t & 63;
    const int wid = t >> 6;
    const int wm = wid >> 1, wn = wid & 1;
    const int r15 = lane & 15, quad = lane >> 4;
    const int sr = t >> 2;
    const int sc = (t & 3) << 3;

    const ushort_t* Ag = A + (size_t)row0 * IDIM;
    const ushort_t* Bgp = Wd + ((size_t)e * DDIM + (size_t)nt * 128) * IDIM;
    const ushort_t* aA  = Ag + (size_t)sr * IDIM + sc;
    const ushort_t* aA2 = Ag + (size_t)(sr + 64) * IDIM + sc;
    const ushort_t* aB  = Bgp + (size_t)sr * IDIM + sc;
    const ushort_t* aB2 = Bgp + (size_t)(sr + 64) * IDIM + sc;
    ushort_t* lA  = ldsA + sr * 32 + sc;  ushort_t* lA2 = ldsA + (sr + 64) * 32 + sc;
    ushort_t* lB  = ldsB + sr * 32 + sc;  ushort_t* lB2 = ldsB + (sr + 64) * 32 + sc;

    for (int k0 = 0; k0 < IDIM; k0 += 32) {
        __syncthreads();
        gload16(aA + k0, lA);   gload16(aA2 + k0, lA2);
        gload16(aB + k0, lB);   gload16(aB2 + k0, lB2);
        __syncthreads();
        short8 af[4], bfv[4];
#pragma unroll
        for (int i = 0; i < 4; ++i) {
            af[i]  = *(const short8*)(ldsA + (wm * 64 + i * 16 + r15) * 32 + quad * 8);
            bfv[i] = *(const short8*)(ldsB + (wn * 64 + i * 16 + r15) * 32 + quad * 8);
        }
#pragma unroll
        for (int mi = 0; mi < 4; ++mi)
#pragma unroll
            for (int ni = 0; ni < 4; ++ni)
                acc[mi][ni] = __builtin_amdgcn_mfma_f32_16x16x32_bf16(af[mi], bfv[ni], acc[mi][ni], 0, 0, 0);
    }

    const int colbase = nt * 128 + wn * 64;
    const int rowbase = row0 + wm * 64;
#pragma unroll
    for (int mi = 0; mi < 4; ++mi) {
#pragma unroll
        for (int r = 0; r < 4; ++r) {
            const int row = rowbase + mi * 16 + quad * 4 + r;
            const float w = row_weight[row];
#pragma unroll
            for (int ni = 0; ni < 4; ++ni) {
                const int col = colbase + ni * 16 + r15;
                contrib[(size_t)row * DDIM + col] = (acc[mi][ni][r] + dwb[e * DDIM + col]) * w;
            }
        }
    }
}

// ---------------- combine 4 contributions per token ----------------
__global__ void combine_kernel(const float* __restrict__ contrib, const int* __restrict__ row_of_pair,
                               float* __restrict__ out) {
    int n = blockIdx.x;
    int t = threadIdx.x;
    int r0 = row_of_pair[n * 4 + 0], r1 = row_of_pair[n * 4 + 1];
    int r2 = row_of_pair[n * 4 + 2], r3 = row_of_pair[n * 4 + 3];
    float4 a = ((const float4*)(contrib + (size_t)r0 * DDIM))[t];
    float4 b = ((const float4*)(contrib + (size_t)r1 * DDIM))[t];
    float4 c = ((const float4*)(contrib + (size_t)r2 * DDIM))[t];
    float4 d = ((const float4*)(contrib + (size_t)r3 * DDIM))[t];
    float4 s;
    s.x = a.x + b.x + c.x + d.x;
    s.y = a.y + b.y + c.y + d.y;
    s.z = a.z + b.z + c.z + d.z;
    s.w = a.w + b.w + c.w + d.w;
    ((float4*)(out + (size_t)n * DDIM))[t] = s;
}

extern "C" void kernel_launch(void* const* d_in, const int* in_sizes, int n_in,
                              void* d_out, int out_size, void* d_ws, size_t ws_size,
                              hipStream_t stream) {
    const float* x   = (const float*)d_in[0];
    const float* rw  = (const float*)d_in[1];
    const float* rb  = (const float*)d_in[2];
    const float* gup = (const float*)d_in[3];
    const float* gub = (const float*)d_in[4];
    const float* dwn = (const float*)d_in[5];
    const float* dwb = (const float*)d_in[6];
    float* out = (float*)d_out;

    char* ws = (char*)d_ws;
    size_t off = 0;
    auto alloc = [&](size_t bytes) -> void* {
        void* p = ws + off;
        off += (bytes + 255) & ~(size_t)255;
        return p;
    };
    ushort_t* Wg   = (ushort_t*)alloc((size_t)ENUM * TWOI * DDIM * 2);  // 67.1 MB
    ushort_t* Wd   = (ushort_t*)alloc((size_t)ENUM * DDIM * IDIM * 2);  // 33.6 MB (contiguous after Wg)
    ushort_t* Ar   = (ushort_t*)alloc((size_t)CAPROWS * DDIM * 2);      // 18.9 MB
    ushort_t* ACT  = (ushort_t*)alloc((size_t)CAPROWS * IDIM * 2);      // 37.7 MB
    float* CONTRIB = (float*)alloc((size_t)CAPROWS * DDIM * 4);         // 37.7 MB
    int*   topk_idx    = (int*)alloc(NTOK * 4 * 4);
    float* topk_w      = (float*)alloc(NTOK * 4 * 4);
    int*   row_of_pair = (int*)alloc(NTOK * 4 * 4);
    int*   row_token   = (int*)alloc(CAPROWS * 4);
    float* row_weight  = (float*)alloc(CAPROWS * 4);
    int*   meta        = (int*)alloc(256);
    int* counts = meta;      int* fill = meta + 8;
    int* base   = meta + 16; int* padcnt = meta + 24;
    int* totalp = meta + 32;

    const int ncvt4 = (ENUM * TWOI * DDIM + ENUM * DDIM * IDIM) / 4;

    zero_meta_kernel<<<1, 64, 0, stream>>>(meta);
    cvt_all_kernel<<<(ncvt4 + 255) / 256, 256, 0, stream>>>(gup, dwn, Wg);
    router_kernel<<<NTOK / 4, 256, 0, stream>>>(x, rw, rb, topk_idx, topk_w, counts);
    assign_kernel<<<NTOK / 256, 256, 0, stream>>>(topk_idx, topk_w, counts, fill,
                                                  row_token, row_weight, row_of_pair,
                                                  base, padcnt, totalp);
    gather_kernel<<<CAPROWS, 256, 0, stream>>>(x, row_token, base, counts, padcnt, totalp, Ar);
    gemm1_kernel<<<dim3(IDIM / 128, 16, ENUM), 256, 0, stream>>>(Ar, Wg, gub, ACT, base, padcnt);
    gemm2_kernel<<<dim3(DDIM / 128, 16, ENUM), 256, 0, stream>>>(ACT, Wd, dwb, row_weight, CONTRIB, base, padcnt);
    combine_kernel<<<NTOK, 256, 0, stream>>>(CONTRIB, row_of_pair, out);
}